// Round 2
// baseline (133.609 us; speedup 1.0000x reference)
//
#include <hip/hip_runtime.h>

#define BS 32768
#define NWP 10
#define DD 256
#define NEXP 6
#define HH 64
#define OUT_DIM 2
#define MB 32   // batch items per gemm block

typedef short bf16x8 __attribute__((ext_vector_type(8)));
typedef float f32x4 __attribute__((ext_vector_type(4)));

__device__ inline unsigned short f2bf(float f) {
  unsigned u = __builtin_bit_cast(unsigned, f);
  u += 0x7fff + ((u >> 16) & 1);   // RNE
  return (unsigned short)(u >> 16);
}

// ---------------- kernel 1: bucket batch indices by expert ----------------
__global__ void bucket_k(const int* __restrict__ cmd,
                         int* __restrict__ counts,
                         unsigned short* __restrict__ lists) {
  const int b = blockIdx.x * 256 + threadIdx.x;   // grid covers exactly BS
  const int e = cmd[b];
  const int lane = threadIdx.x & 63;
  #pragma unroll
  for (int ee = 0; ee < NEXP; ++ee) {
    unsigned long long m = __ballot(e == ee);
    if (e == ee) {
      const int leader = __ffsll((long long)m) - 1;
      const int nbelow = __popcll(m & ((1ull << lane) - 1ull));
      int base = 0;
      if (lane == leader) base = atomicAdd(&counts[ee], __popcll(m));
      base = __shfl(base, leader);   // leader IS active in this branch -> defined
      lists[ee * BS + base + nbelow] = (unsigned short)b;
    }
  }
}

// ---------------- kernel 2: per-expert fused GEMM ----------------
__global__ __launch_bounds__(256, 2) void moe_gemm_k(
    const float* __restrict__ x,
    const float* __restrict__ rank_embed,
    const float* __restrict__ W1,
    const float* __restrict__ b1,
    const float* __restrict__ W2,
    const float* __restrict__ b2,
    const int* __restrict__ counts,
    const unsigned short* __restrict__ lists,
    float* __restrict__ out)
{
  __shared__ short Wb[HH * DD];       // W1[e]^T as bf16, [h][d], XOR-swizzled
  __shared__ short Xa[4][16 * DD];    // per-wave 16-row x tiles, swizzled

  const int e = blockIdx.y;
  const int cnt = counts[e];
  const int start = blockIdx.x * MB;
  if (start >= cnt) return;
  const int nb = min(MB, cnt - start);
  const int nrows = nb * NWP;

  const int tid = threadIdx.x;
  const int lane = tid & 63;
  const int wv = tid >> 6;

  // stage W1[e] transposed into LDS (bf16), swizzle: shortIdx ^= (h&7)<<3
  {
    const int h = tid & 63;
    const int dblk = tid >> 6;                       // 0..3
    const float* wp = W1 + (size_t)e * DD * HH + h;  // stride HH over d
    #pragma unroll
    for (int i = 0; i < 16; ++i) {
      const int d = dblk * 64 + i * 4;
      const float w0 = wp[(size_t)(d + 0) * HH];
      const float w1v = wp[(size_t)(d + 1) * HH];
      const float w2v = wp[(size_t)(d + 2) * HH];
      const float w3v = wp[(size_t)(d + 3) * HH];
      short4 pk = make_short4((short)f2bf(w0), (short)f2bf(w1v),
                              (short)f2bf(w2v), (short)f2bf(w3v));
      *(short4*)&Wb[h * DD + (d ^ ((h & 7) << 3))] = pk;
    }
  }

  // batch ids held in registers of lanes 0..31, broadcast via shfl
  int bid_reg = 0;
  if (lane < nb) bid_reg = (int)lists[e * BS + start + lane];

  __syncthreads();

  const int arow = lane & 15;
  const int ag = lane >> 4;

  for (int c = wv; c * 16 < nrows; c += 4) {
    const int r0 = c * 16;
    short* Xw = Xa[wv];

    // stage 16 rows of xr = x + rank_embed as bf16 (per-wave buffer, no barrier)
    #pragma unroll
    for (int r = 0; r < 16; ++r) {
      const int rowc = min(r0 + r, nrows - 1);
      const int bi = rowc / 10;
      const int n = rowc % 10;
      const int gb = __shfl(bid_reg, bi);            // uniform src, all lanes active
      const float4 xv = *(const float4*)(x + ((size_t)gb * NWP + n) * DD + lane * 4);
      const float4 rv = *(const float4*)(rank_embed + n * DD + lane * 4);
      short4 pk = make_short4((short)f2bf(xv.x + rv.x), (short)f2bf(xv.y + rv.y),
                              (short)f2bf(xv.z + rv.z), (short)f2bf(xv.w + rv.w));
      *(short4*)&Xw[r * DD + ((lane * 4) ^ ((r & 7) << 3))] = pk;
    }

    // 16x64 output tile via MFMA, K=256 in 8 steps
    f32x4 acc[4] = {{0,0,0,0},{0,0,0,0},{0,0,0,0},{0,0,0,0}};
    #pragma unroll
    for (int ks = 0; ks < 8; ++ks) {
      const int kb = ks * 32 + ag * 8;               // k base (shorts)
      bf16x8 a = *(bf16x8*)&Xw[arow * DD + (kb ^ ((arow & 7) << 3))];
      #pragma unroll
      for (int nt = 0; nt < 4; ++nt) {
        const int h = nt * 16 + arow;
        bf16x8 bv = *(bf16x8*)&Wb[h * DD + (kb ^ ((h & 7) << 3))];
        acc[nt] = __builtin_amdgcn_mfma_f32_16x16x32_bf16(a, bv, acc[nt], 0, 0, 0);
      }
    }

    // epilogue: relu(acc + b1) @ W2, reduce over the 16 h-lanes
    float po[4][2] = {{0,0},{0,0},{0,0},{0,0}};
    #pragma unroll
    for (int nt = 0; nt < 4; ++nt) {
      const int col = nt * 16 + arow;
      const float b1v = b1[e * HH + col];
      const float w20 = W2[((size_t)e * HH + col) * OUT_DIM + 0];
      const float w21 = W2[((size_t)e * HH + col) * OUT_DIM + 1];
      #pragma unroll
      for (int rg = 0; rg < 4; ++rg) {
        const float hv = fmaxf(acc[nt][rg] + b1v, 0.0f);
        po[rg][0] += hv * w20;
        po[rg][1] += hv * w21;
      }
    }
    #pragma unroll
    for (int off = 1; off < 16; off <<= 1) {
      #pragma unroll
      for (int rg = 0; rg < 4; ++rg) {
        po[rg][0] += __shfl_xor(po[rg][0], off);
        po[rg][1] += __shfl_xor(po[rg][1], off);
      }
    }
    // FIX (round 1 bug): do the bid broadcast with ALL lanes active.
    // Previously this shfl sat inside `if (arow == 0)` with a lane-dependent
    // source index -> ds_bpermute from inactive lanes -> undefined gb ->
    // stores scattered to garbage, output mostly zeros (absmax == max|ref|).
    const float bb0 = b2[e * OUT_DIM + 0];
    const float bb1 = b2[e * OUT_DIM + 1];
    #pragma unroll
    for (int rg = 0; rg < 4; ++rg) {
      const int row = r0 + ag * 4 + rg;
      const int rowc2 = min(row, nrows - 1);
      const int gb = __shfl(bid_reg, rowc2 / 10);    // all 64 lanes participate
      if (arow == 0 && row < nrows) {
        const int n = rowc2 % 10;
        *(float2*)(out + ((size_t)gb * NWP + n) * OUT_DIM) =
            make_float2(po[rg][0] + bb0, po[rg][1] + bb1);
      }
    }
  }
}

// ---------------- kernel 3: in-place cumsum over waypoints ----------------
__global__ void cumsum_k(float* __restrict__ out) {
  const int b = blockIdx.x * 256 + threadIdx.x;
  float* p = out + (size_t)b * (NWP * OUT_DIM);
  float2 q[NWP];
  #pragma unroll
  for (int n = 0; n < NWP; ++n) q[n] = *(float2*)(p + n * 2);
  float s0 = 0.f, s1 = 0.f;
  #pragma unroll
  for (int n = 0; n < NWP; ++n) {
    s0 += q[n].x; s1 += q[n].y;
    q[n].x = s0;  q[n].y = s1;
  }
  #pragma unroll
  for (int n = 0; n < NWP; ++n) *(float2*)(p + n * 2) = q[n];
}

extern "C" void kernel_launch(void* const* d_in, const int* in_sizes, int n_in,
                              void* d_out, int out_size, void* d_ws, size_t ws_size,
                              hipStream_t stream) {
  const float* x          = (const float*)d_in[0];
  const int*   meas       = (const int*)d_in[1];
  const float* rank_embed = (const float*)d_in[2];
  const float* W1         = (const float*)d_in[3];
  const float* b1         = (const float*)d_in[4];
  const float* W2         = (const float*)d_in[5];
  const float* b2         = (const float*)d_in[6];
  float* out = (float*)d_out;

  int* counts = (int*)d_ws;                                    // 6 ints
  unsigned short* lists = (unsigned short*)((char*)d_ws + 256); // 6*BS ushort

  hipMemsetAsync(d_ws, 0, 256, stream);
  bucket_k<<<BS / 256, 256, 0, stream>>>(meas, counts, lists);
  dim3 gg((BS + MB - 1) / MB, NEXP);
  moe_gemm_k<<<gg, 256, 0, stream>>>(x, rank_embed, W1, b1, W2, b2,
                                     counts, lists, out);
  cumsum_k<<<BS / 256, 256, 0, stream>>>(out);
}